// Round 1
// baseline (1795.039 us; speedup 1.0000x reference)
//
#include <hip/hip_runtime.h>
#include <hip/hip_bf16.h>
#include <math.h>

#define NHEADS 8
#define CDIM 256
#define DHEAD 32
#define NTOK 2304   // 48*48
#define BATCH 4
#define SCALE 0.17677669529663687f  // (256/8)^-0.5

// ---------------------------------------------------------------------------
// GEMM: Y[o,n] = sum_c W[o,c] * X[b,c,n]  (+ bias for proj path)
// QKV=true : O=768, scatter into q/k/v  (d0,d1,d2)
// QKV=false: O=256, write d0 with bias
// grid: (NTOK/64, O/64, BATCH), block: 256
// ---------------------------------------------------------------------------
template <bool QKV>
__global__ __launch_bounds__(256) void gemm256(const float* __restrict__ W,
                                               const float* __restrict__ X,
                                               float* __restrict__ d0,
                                               float* __restrict__ d1,
                                               float* __restrict__ d2,
                                               const float* __restrict__ bias) {
  __shared__ float Ws[16][65];
  __shared__ float Xs[16][65];
  const int tid = threadIdx.x;
  const int tx = tid & 15, ty = tid >> 4;
  const int nt = blockIdx.x * 64;
  const int ot = blockIdx.y * 64;
  const int b  = blockIdx.z;
  const float* Xb = X + (size_t)b * CDIM * NTOK;

  float acc[4][4];
#pragma unroll
  for (int i = 0; i < 4; ++i)
#pragma unroll
    for (int j = 0; j < 4; ++j) acc[i][j] = 0.f;

  for (int k0 = 0; k0 < CDIM; k0 += 16) {
#pragma unroll
    for (int p = 0; p < 4; ++p) {
      int idx = tid + p * 256;  // 0..1023
      int kk = idx & 15, oo = idx >> 4;
      Ws[kk][oo] = W[(ot + oo) * CDIM + k0 + kk];
      int nn = idx & 63, k2 = idx >> 6;
      Xs[k2][nn] = Xb[(k0 + k2) * NTOK + nt + nn];
    }
    __syncthreads();
#pragma unroll
    for (int kk = 0; kk < 16; ++kk) {
      float a[4], bb[4];
#pragma unroll
      for (int i = 0; i < 4; ++i) a[i] = Ws[kk][ty * 4 + i];
#pragma unroll
      for (int j = 0; j < 4; ++j) bb[j] = Xs[kk][tx * 4 + j];
#pragma unroll
      for (int i = 0; i < 4; ++i)
#pragma unroll
        for (int j = 0; j < 4; ++j) acc[i][j] = fmaf(a[i], bb[j], acc[i][j]);
    }
    __syncthreads();
  }

#pragma unroll
  for (int i = 0; i < 4; ++i) {
    int o = ot + ty * 4 + i;
    float badd = 0.f;
    if constexpr (!QKV) badd = bias[o];
    int s = o >> 8, rem = o & 255;
    float* dst;
    if constexpr (QKV)
      dst = (s == 0) ? d0 : ((s == 1) ? d1 : d2);
    else
      dst = d0;
#pragma unroll
    for (int j = 0; j < 4; ++j) {
      int n = nt + tx * 4 + j;
      dst[((size_t)b * CDIM + rem) * NTOK + n] = acc[i][j] + badd;
    }
  }
}

// ---------------------------------------------------------------------------
// Flash-style attention. One wave (64 lanes) per query row i of one (b,h).
// Per-lane online softmax over its j-subset, butterfly merge at the end.
// grid: BATCH*NHEADS*(NTOK/4), block: 256 (4 waves -> 4 rows per block)
// q,k,v layout: [(b*8+h)*32 + d][n]
// ---------------------------------------------------------------------------
__global__ __launch_bounds__(256) void attn_kernel(const float* __restrict__ q,
                                                   const float* __restrict__ k,
                                                   const float* __restrict__ v,
                                                   float* __restrict__ ao) {
  const int tid = threadIdx.x;
  const int wave = tid >> 6, lane = tid & 63;
  const int tile = blockIdx.x % (NTOK / 4);
  const int bh = blockIdx.x / (NTOK / 4);
  const int i = tile * 4 + wave;
  const float* qb = q + (size_t)bh * DHEAD * NTOK;
  const float* kb = k + (size_t)bh * DHEAD * NTOK;
  const float* vb = v + (size_t)bh * DHEAD * NTOK;

  float qv[DHEAD];
#pragma unroll
  for (int d = 0; d < DHEAD; ++d) qv[d] = qb[d * NTOK + i] * SCALE;

  float m = -INFINITY, l = 0.f;
  float acc[DHEAD];
#pragma unroll
  for (int d = 0; d < DHEAD; ++d) acc[d] = 0.f;

  for (int it = 0; it < NTOK / 64; ++it) {
    const int j = it * 64 + lane;
    float s = 0.f;
#pragma unroll
    for (int d = 0; d < DHEAD; ++d) s = fmaf(qv[d], kb[d * NTOK + j], s);
    float vv[DHEAD];
#pragma unroll
    for (int d = 0; d < DHEAD; ++d) vv[d] = vb[d * NTOK + j];
    if (s > m) {
      float c = __expf(m - s);  // exp(-inf)=0 handles first iteration
      l = l * c + 1.f;
#pragma unroll
      for (int d = 0; d < DHEAD; ++d) acc[d] = fmaf(acc[d], c, vv[d]);
      m = s;
    } else {
      float p = __expf(s - m);
      l += p;
#pragma unroll
      for (int d = 0; d < DHEAD; ++d) acc[d] = fmaf(p, vv[d], acc[d]);
    }
  }

  // merge the 64 per-lane online-softmax states
  float M = m;
#pragma unroll
  for (int off = 32; off; off >>= 1) M = fmaxf(M, __shfl_xor(M, off, 64));
  const float f = __expf(m - M);
  l *= f;
#pragma unroll
  for (int off = 32; off; off >>= 1) l += __shfl_xor(l, off, 64);

  float ov = 0.f;
#pragma unroll
  for (int d = 0; d < DHEAD; ++d) {
    float sacc = acc[d] * f;
#pragma unroll
    for (int off = 32; off; off >>= 1) sacc += __shfl_xor(sacc, off, 64);
    if (lane == d) ov = sacc;  // compile-time d -> predicated select, no scratch
  }
  if (lane < DHEAD) ao[((size_t)bh * DHEAD + lane) * NTOK + i] = ov / l;
}

// ---------------------------------------------------------------------------
extern "C" void kernel_launch(void* const* d_in, const int* in_sizes, int n_in,
                              void* d_out, int out_size, void* d_ws, size_t ws_size,
                              hipStream_t stream) {
  const float* x      = (const float*)d_in[0];
  const float* w_qkv  = (const float*)d_in[1];
  const float* w_proj = (const float*)d_in[2];
  const float* b_proj = (const float*)d_in[3];
  float* out = (float*)d_out;

  float* ws = (float*)d_ws;
  const size_t per = (size_t)BATCH * CDIM * NTOK;  // 2,359,296 floats
  float* q  = ws;
  float* k  = q + per;
  float* v  = k + per;
  float* ao = v + per;

  dim3 g1(NTOK / 64, (3 * CDIM) / 64, BATCH);
  gemm256<true><<<g1, 256, 0, stream>>>(w_qkv, x, q, k, v, nullptr);

  attn_kernel<<<BATCH * NHEADS * (NTOK / 4), 256, 0, stream>>>(q, k, v, ao);

  dim3 g3(NTOK / 64, CDIM / 64, BATCH);
  gemm256<false><<<g3, 256, 0, stream>>>(w_proj, ao, out, nullptr, nullptr, b_proj);
}

// Round 2
// 250.336 us; speedup vs baseline: 7.1705x; 7.1705x over previous
//
#include <hip/hip_runtime.h>
#include <hip/hip_bf16.h>
#include <math.h>

#define NHEADS 8
#define CDIM 256
#define DHEAD 32
#define NTOK 2304   // 48*48
#define BATCH 4
#define NBH 32      // BATCH*NHEADS
#define NJT 36      // NTOK/64
#define SCALE 0.17677669529663687f  // (256/8)^-0.5

typedef __attribute__((ext_vector_type(8))) short short8;
typedef __attribute__((ext_vector_type(4))) float f32x4;
typedef __attribute__((ext_vector_type(4))) unsigned short ushort4v;

__device__ inline unsigned short bf16r(float x) {
  __hip_bfloat16 h = __float2bfloat16(x);
  return *reinterpret_cast<unsigned short*>(&h);
}
__device__ inline float bf16f(unsigned short u) {
  __hip_bfloat16 h = *reinterpret_cast<__hip_bfloat16*>(&u);
  return __bfloat162float(h);
}

// ---------------------------------------------------------------------------
// GEMM: Y[o,n] = sum_c W[o,c] * X[b,c,n]
// MODE 0: O=768 -> qkv. Epilogue writes bf16 hi/lo splits:
//   q,k: [bh][n][64] (hi chunks 0..3, lo chunks 4..7), 16B-chunk XOR-swizzled by (n&7)
//   v  : [bh][jt][d][64] jt-blocked, chunk-swizzled by (d&7)   (single bf16)
// MODE 1: O=256 -> fp32 out + bias (proj)
// grid: (NTOK/64, O/64, BATCH), block 256
// ---------------------------------------------------------------------------
template <int MODE>
__global__ __launch_bounds__(256) void gemm256(const float* __restrict__ W,
                                               const float* __restrict__ X,
                                               unsigned short* __restrict__ qhl,
                                               unsigned short* __restrict__ khl,
                                               unsigned short* __restrict__ vhl,
                                               float* __restrict__ outp,
                                               const float* __restrict__ bias) {
  __shared__ float Ws[16][65];
  __shared__ float Xs[16][65];
  const int tid = threadIdx.x;
  const int tx = tid & 15, ty = tid >> 4;
  const int nt = blockIdx.x * 64;
  const int ot = blockIdx.y * 64;
  const int b  = blockIdx.z;
  const float* Xb = X + (size_t)b * CDIM * NTOK;

  float acc[4][4];
#pragma unroll
  for (int i = 0; i < 4; ++i)
#pragma unroll
    for (int j = 0; j < 4; ++j) acc[i][j] = 0.f;

  for (int k0 = 0; k0 < CDIM; k0 += 16) {
#pragma unroll
    for (int p = 0; p < 4; ++p) {
      int idx = tid + p * 256;
      int kk = idx & 15, oo = idx >> 4;
      Ws[kk][oo] = W[(ot + oo) * CDIM + k0 + kk];
      int nn = idx & 63, k2 = idx >> 6;
      Xs[k2][nn] = Xb[(k0 + k2) * NTOK + nt + nn];
    }
    __syncthreads();
#pragma unroll
    for (int kk = 0; kk < 16; ++kk) {
      float a[4], bb[4];
#pragma unroll
      for (int i = 0; i < 4; ++i) a[i] = Ws[kk][ty * 4 + i];
#pragma unroll
      for (int j = 0; j < 4; ++j) bb[j] = Xs[kk][tx * 4 + j];
#pragma unroll
      for (int i = 0; i < 4; ++i)
#pragma unroll
        for (int j = 0; j < 4; ++j) acc[i][j] = fmaf(a[i], bb[j], acc[i][j]);
    }
    __syncthreads();
  }

  if constexpr (MODE == 0) {
    const int o0 = ot + ty * 4;       // 4 consecutive o's for this thread
    const int s  = o0 >> 8;           // 0=q 1=k 2=v (uniform for the 4)
    const int h  = (o0 >> 5) & 7;
    const int d0 = o0 & 31;           // multiple of 4
    const int bh = b * 8 + h;
    if (s < 2) {
      unsigned short* dst = (s == 0) ? qhl : khl;
      const float sc = (s == 0) ? SCALE : 1.0f;
      const int ch = d0 >> 3, el = d0 & 7;  // el in {0,4}
#pragma unroll
      for (int j = 0; j < 4; ++j) {
        const int n = nt + tx * 4 + j;
        ushort4v hv, lv;
#pragma unroll
        for (int i = 0; i < 4; ++i) {
          float v = acc[i][j] * sc;
          unsigned short h16 = bf16r(v);
          hv[i] = h16;
          lv[i] = bf16r(v - bf16f(h16));
        }
        const size_t row = ((size_t)bh * NTOK + n) * 64;
        const int sw = n & 7;
        *(ushort4v*)&dst[row + (size_t)(((ch    ) ^ sw) << 3) + el] = hv;
        *(ushort4v*)&dst[row + (size_t)(((ch + 4) ^ sw) << 3) + el] = lv;
      }
    } else {
      const int n0 = nt + tx * 4;
      const int jt = n0 >> 6, jl0 = n0 & 63;  // jl0 multiple of 4, same chunk
#pragma unroll
      for (int i = 0; i < 4; ++i) {
        const int d = d0 + i;
        ushort4v v4;
#pragma unroll
        for (int j = 0; j < 4; ++j) v4[j] = bf16r(acc[i][j]);
        const size_t base = (((size_t)bh * NJT + jt) * 32 + d) * 64;
        *(ushort4v*)&vhl[base + (size_t)((((jl0 >> 3) ^ (d & 7))) << 3) + (jl0 & 7)] = v4;
      }
    }
  } else {
#pragma unroll
    for (int i = 0; i < 4; ++i) {
      const int o = ot + ty * 4 + i;
      const float badd = bias[o];
#pragma unroll
      for (int j = 0; j < 4; ++j) {
        const int n = nt + tx * 4 + j;
        outp[((size_t)b * CDIM + o) * NTOK + n] = acc[i][j] + badd;
      }
    }
  }
}

// ---------------------------------------------------------------------------
// MFMA flash attention. Block = 256 thr (4 waves), each wave owns 16 q-rows.
// j-loop over 64-token K/V tiles staged in LDS via global_load_lds.
// QK^T: 3-way hi/lo split MFMA. PV: single bf16 via per-wave swizzled P in LDS.
// grid: (NTOK/64, NBH)
// ---------------------------------------------------------------------------
__global__ __launch_bounds__(256) void attn_mfma(const unsigned short* __restrict__ qhl,
                                                 const unsigned short* __restrict__ khl,
                                                 const unsigned short* __restrict__ vhl,
                                                 float* __restrict__ ao) {
  __shared__ __align__(128) unsigned short Kt[64 * 64];     // 8 KB
  __shared__ __align__(128) unsigned short Vt[32 * 64];     // 4 KB
  __shared__ __align__(128) unsigned short Pt[4][16 * 64];  // 8 KB

  const int tid = threadIdx.x;
  const int w = tid >> 6, L = tid & 63;
  const int g = L >> 4, li = L & 15, sw = L & 7;
  const int bh = blockIdx.y;
  const int i0 = blockIdx.x * 64 + w * 16;

  // Q fragments (A-operand): row = li, k(d) = g*8+e ; global layout pre-swizzled
  const size_t qrow = ((size_t)bh * NTOK + i0 + li) * 64;
  const short8 qhi = *(const short8*)&qhl[qrow + (size_t)((g ^ sw) << 3)];
  const short8 qlo = *(const short8*)&qhl[qrow + (size_t)(((g + 4) ^ sw) << 3)];

  f32x4 oacc0 = {0.f, 0.f, 0.f, 0.f};
  f32x4 oacc1 = {0.f, 0.f, 0.f, 0.f};
  float m[4], l[4];
#pragma unroll
  for (int r = 0; r < 4; ++r) { m[r] = -INFINITY; l[r] = 0.f; }

  const char* kslab = (const char*)(khl + (size_t)bh * NTOK * 64);
  const char* vslab = (const char*)(vhl + (size_t)bh * NJT * 2048);
  unsigned short* pw = Pt[w];

  for (int jt = 0; jt < NJT; ++jt) {
    __syncthreads();  // all waves done reading previous tile
    {
      const char* ks = kslab + (size_t)jt * 8192;
      const int off = w * 2048;
      __builtin_amdgcn_global_load_lds(
          (const __attribute__((address_space(1))) unsigned int*)(ks + off + L * 16),
          (__attribute__((address_space(3))) unsigned int*)((char*)Kt + off), 16, 0, 0);
      __builtin_amdgcn_global_load_lds(
          (const __attribute__((address_space(1))) unsigned int*)(ks + off + 1024 + L * 16),
          (__attribute__((address_space(3))) unsigned int*)((char*)Kt + off + 1024), 16, 0, 0);
      const char* vs = vslab + (size_t)jt * 4096;
      __builtin_amdgcn_global_load_lds(
          (const __attribute__((address_space(1))) unsigned int*)(vs + w * 1024 + L * 16),
          (__attribute__((address_space(3))) unsigned int*)((char*)Vt + w * 1024), 16, 0, 0);
    }
    __syncthreads();  // staged data visible (vmcnt drained by syncthreads)

    // ---- QK^T: 4 j-tiles of 16, 3-way split ----
    f32x4 sc4[4];
#pragma unroll
    for (int t = 0; t < 4; ++t) {
      const int row = t * 16 + li;  // row&7 == sw
      const char* kr = (const char*)Kt + row * 128;
      const short8 khi = *(const short8*)(kr + (((g    ) ^ sw) << 4));
      const short8 klo = *(const short8*)(kr + (((g + 4) ^ sw) << 4));
      f32x4 c = {0.f, 0.f, 0.f, 0.f};
      c = __builtin_amdgcn_mfma_f32_16x16x32_bf16(qhi, khi, c, 0, 0, 0);
      c = __builtin_amdgcn_mfma_f32_16x16x32_bf16(qlo, khi, c, 0, 0, 0);
      c = __builtin_amdgcn_mfma_f32_16x16x32_bf16(qhi, klo, c, 0, 0, 0);
      sc4[t] = c;
    }

    // ---- online softmax (rows 4g+r, cols across 16 lanes of the group) ----
#pragma unroll
    for (int r = 0; r < 4; ++r) {
      float mx = fmaxf(fmaxf(sc4[0][r], sc4[1][r]), fmaxf(sc4[2][r], sc4[3][r]));
#pragma unroll
      for (int off = 1; off < 16; off <<= 1) mx = fmaxf(mx, __shfl_xor(mx, off, 64));
      const float nm = fmaxf(m[r], mx);
      const float corr = __expf(m[r] - nm);  // 0 on first tile (m=-inf)
      m[r] = nm;
      const int il = g * 4 + r;
      float psum = 0.f;
#pragma unroll
      for (int t = 0; t < 4; ++t) {
        const float p = __expf(sc4[t][r] - nm);
        psum += p;
        pw[il * 64 + (((t * 2 + (li >> 3)) ^ (il & 7)) << 3) + (li & 7)] = bf16r(p);
      }
#pragma unroll
      for (int off = 1; off < 16; off <<= 1) psum += __shfl_xor(psum, off, 64);
      l[r] = l[r] * corr + psum;
      oacc0[r] *= corr;
      oacc1[r] *= corr;
    }

    // ---- PV: out[i][d] += P[i][j] * V[j][d] ----
#pragma unroll
    for (int ksb = 0; ksb < 2; ++ksb) {
      const short8 pa = *(const short8*)((const char*)pw + li * 128 + (((ksb * 4 + g) ^ sw) << 4));
      const short8 vb0 = *(const short8*)((const char*)Vt + li * 128 + (((ksb * 4 + g) ^ sw) << 4));
      const short8 vb1 = *(const short8*)((const char*)Vt + (16 + li) * 128 + (((ksb * 4 + g) ^ sw) << 4));
      oacc0 = __builtin_amdgcn_mfma_f32_16x16x32_bf16(pa, vb0, oacc0, 0, 0, 0);
      oacc1 = __builtin_amdgcn_mfma_f32_16x16x32_bf16(pa, vb1, oacc1, 0, 0, 0);
    }
  }

  // ---- epilogue: out[i=4g+r][d], rescale by 1/l, write ao[b][h*32+d][n] ----
#pragma unroll
  for (int r = 0; r < 4; ++r) {
    const float inv = 1.f / l[r];
    const int ig = i0 + g * 4 + r;
    ao[((size_t)bh * 32 + li) * NTOK + ig]        = oacc0[r] * inv;
    ao[((size_t)bh * 32 + 16 + li) * NTOK + ig]   = oacc1[r] * inv;
  }
}

// ---------------------------------------------------------------------------
extern "C" void kernel_launch(void* const* d_in, const int* in_sizes, int n_in,
                              void* d_out, int out_size, void* d_ws, size_t ws_size,
                              hipStream_t stream) {
  const float* x      = (const float*)d_in[0];
  const float* w_qkv  = (const float*)d_in[1];
  const float* w_proj = (const float*)d_in[2];
  const float* b_proj = (const float*)d_in[3];
  float* out = (float*)d_out;

  const size_t per = (size_t)BATCH * CDIM * NTOK;  // 2,359,296
  float* ao = (float*)d_ws;
  unsigned short* qhl = (unsigned short*)(ao + per);
  unsigned short* khl = qhl + (size_t)NBH * NTOK * 64;
  unsigned short* vhl = khl + (size_t)NBH * NTOK * 64;

  dim3 g1(NTOK / 64, (3 * CDIM) / 64, BATCH);
  gemm256<0><<<g1, 256, 0, stream>>>(w_qkv, x, qhl, khl, vhl, nullptr, nullptr);

  dim3 g2(NTOK / 64, NBH);
  attn_mfma<<<g2, 256, 0, stream>>>(qhl, khl, vhl, ao);

  dim3 g3(NTOK / 64, CDIM / 64, BATCH);
  gemm256<1><<<g3, 256, 0, stream>>>(w_proj, ao, nullptr, nullptr, nullptr, out, b_proj);
}

// Round 3
// 139.899 us; speedup vs baseline: 12.8310x; 1.7894x over previous
//
#include <hip/hip_runtime.h>
#include <hip/hip_bf16.h>
#include <math.h>

#define NHEADS 8
#define CDIM 256
#define NTOK 2304   // 48*48
#define BATCH 4
#define NBH 32      // BATCH*NHEADS
#define NJT 36      // NTOK/64 (j tiles)
#define NNT 36      // n tiles
#define SCALE 0.17677669529663687f  // (256/8)^-0.5

typedef __attribute__((ext_vector_type(8))) short short8;
typedef __attribute__((ext_vector_type(4))) float f32x4;

__device__ inline unsigned short bf16r(float x) {
  __hip_bfloat16 h = __float2bfloat16(x);
  return *reinterpret_cast<unsigned short*>(&h);
}
__device__ inline float bf16f(unsigned short u) {
  __hip_bfloat16 h;
  *reinterpret_cast<unsigned short*>(&h) = u;
  return __bfloat162float(h);
}
__device__ inline void split_hl(float x, unsigned short& h, unsigned short& l) {
  h = bf16r(x);
  l = bf16r(x - bf16f(h));
}
__device__ inline void glds16(const char* src, char* ldsbase) {
  __builtin_amdgcn_global_load_lds(
      (const __attribute__((address_space(1))) unsigned int*)src,
      (__attribute__((address_space(3))) unsigned int*)ldsbase, 16, 0, 0);
}

// ---------------------------------------------------------------------------
// prep_w: split W rows into bf16 hi/lo, tiled+swizzled operand layout
//   dst[otile][kc][64 rows][8 slots][8]  slot = chunk ^ (row&7); chunks 0-3 hi, 4-7 lo
// grid (otiles, 8), block 256
// ---------------------------------------------------------------------------
__global__ __launch_bounds__(256) void prep_w(const float* __restrict__ W,
                                              unsigned short* __restrict__ dst,
                                              int scale_below, float qscale) {
  __shared__ float T[64 * 36];
  const int tid = threadIdx.x;
  const int otile = blockIdx.x, kc = blockIdx.y;
#pragma unroll
  for (int p = 0; p < 8; ++p) {
    int idx = p * 256 + tid;
    int c = idx & 31, o = idx >> 5;
    float v = W[(size_t)(otile * 64 + o) * CDIM + kc * 32 + c];
    if (otile * 64 + o < scale_below) v *= qscale;
    T[o * 36 + c] = v;
  }
  __syncthreads();
  const int o = tid & 63, coct = tid >> 6;  // 0..3
  short8 h8, l8;
#pragma unroll
  for (int e = 0; e < 8; ++e) {
    unsigned short h, l;
    split_hl(T[o * 36 + coct * 8 + e], h, l);
    h8[e] = (short)h;
    l8[e] = (short)l;
  }
  unsigned short* base = dst + ((size_t)(otile * 8 + kc)) * 4096 + o * 64;
  *(short8*)&base[(coct ^ (o & 7)) << 3] = h8;
  *(short8*)&base[((coct + 4) ^ (o & 7)) << 3] = l8;
}

// ---------------------------------------------------------------------------
// prep_x: transpose + split x[b][c][n] -> xhl[b][ntile][kc][64 n][8 slots][8]
// grid (36, 8, 4), block 256
// ---------------------------------------------------------------------------
__global__ __launch_bounds__(256) void prep_x(const float* __restrict__ x,
                                              unsigned short* __restrict__ xhl) {
  __shared__ float T[64 * 36];
  const int tid = threadIdx.x;
  const int ntile = blockIdx.x, kc = blockIdx.y, b = blockIdx.z;
#pragma unroll
  for (int p = 0; p < 8; ++p) {
    int idx = p * 256 + tid;
    int n = idx & 63, c = idx >> 6;
    T[n * 36 + c] = x[((size_t)(b * CDIM + kc * 32 + c)) * NTOK + ntile * 64 + n];
  }
  __syncthreads();
  const int n = tid & 63, coct = tid >> 6;
  short8 h8, l8;
#pragma unroll
  for (int e = 0; e < 8; ++e) {
    unsigned short h, l;
    split_hl(T[n * 36 + coct * 8 + e], h, l);
    h8[e] = (short)h;
    l8[e] = (short)l;
  }
  unsigned short* base = xhl + ((size_t)((b * NNT + ntile) * 8 + kc)) * 4096 + n * 64;
  *(short8*)&base[(coct ^ (n & 7)) << 3] = h8;
  *(short8*)&base[((coct + 4) ^ (n & 7)) << 3] = l8;
}

// ---------------------------------------------------------------------------
// MFMA GEMM, 64x64 tile, K=256, bf16 hi/lo 3-product split, 2-phase pipeline.
// MODE 0: qkv -> write qhl/khl (hi/lo swizzled [bh][n][64]) and vhl ([bh][jt][32][64])
// MODE 1: proj -> fp32 out + bias
// grid (36, otiles, 4), block 256
// ---------------------------------------------------------------------------
template <int MODE>
__global__ __launch_bounds__(256) void gemm_mfma(const unsigned short* __restrict__ Ahl,
                                                 const unsigned short* __restrict__ Bhl,
                                                 unsigned short* __restrict__ qhl,
                                                 unsigned short* __restrict__ khl,
                                                 unsigned short* __restrict__ vhl,
                                                 float* __restrict__ outp,
                                                 const float* __restrict__ bias) {
  __shared__ __align__(128) char smem[32768];
  const int tid = threadIdx.x;
  const int w = tid >> 6, L = tid & 63;
  const int g = L >> 4, li = L & 15, sw = li & 7;
  const int ntile = blockIdx.x, otile = blockIdx.y, b = blockIdx.z;
  const char* Asrc = (const char*)(Ahl + (size_t)otile * 8 * 4096);
  const char* Bsrc = (const char*)(Bhl + (size_t)((b * NNT + ntile) * 8) * 4096);

  f32x4 acc[4];
#pragma unroll
  for (int t = 0; t < 4; ++t) acc[t] = (f32x4){0.f, 0.f, 0.f, 0.f};

  auto stage = [&](int kc, int p) {
    const char* as = Asrc + (size_t)kc * 8192;
    const char* bs = Bsrc + (size_t)kc * 8192;
    char* ad = smem + p * 16384;
    char* bd = ad + 8192;
    glds16(as + w * 2048 + L * 16, ad + w * 2048);
    glds16(as + w * 2048 + 1024 + L * 16, ad + w * 2048 + 1024);
    glds16(bs + w * 2048 + L * 16, bd + w * 2048);
    glds16(bs + w * 2048 + 1024 + L * 16, bd + w * 2048 + 1024);
  };

  stage(0, 0);
  for (int kc = 0; kc < 8; ++kc) {
    __syncthreads();  // stage(kc) visible; previous compute done
    if (kc < 7) stage(kc + 1, (kc + 1) & 1);
    const char* ab = smem + (kc & 1) * 16384;
    const char* bb = ab + 8192;
    const char* ar = ab + (w * 16 + li) * 128;
    const short8 ahi = *(const short8*)(ar + ((g ^ sw) << 4));
    const short8 alo = *(const short8*)(ar + (((g + 4) ^ sw) << 4));
#pragma unroll
    for (int t = 0; t < 4; ++t) {
      const char* br = bb + (t * 16 + li) * 128;
      const short8 bhi = *(const short8*)(br + ((g ^ sw) << 4));
      const short8 blo = *(const short8*)(br + (((g + 4) ^ sw) << 4));
      acc[t] = __builtin_amdgcn_mfma_f32_16x16x32_bf16(ahi, bhi, acc[t], 0, 0, 0);
      acc[t] = __builtin_amdgcn_mfma_f32_16x16x32_bf16(alo, bhi, acc[t], 0, 0, 0);
      acc[t] = __builtin_amdgcn_mfma_f32_16x16x32_bf16(ahi, blo, acc[t], 0, 0, 0);
    }
  }

  if constexpr (MODE == 1) {
#pragma unroll
    for (int t = 0; t < 4; ++t)
#pragma unroll
      for (int r = 0; r < 4; ++r) {
        const int o = otile * 64 + w * 16 + g * 4 + r;
        outp[((size_t)(b * CDIM + o)) * NTOK + ntile * 64 + t * 16 + li] =
            acc[t][r] + bias[o];
      }
  } else {
    // bounce through LDS: T[64 n][68 words] (16B-aligned rows, bank-spread)
    __syncthreads();
    float* T = (float*)smem;
#pragma unroll
    for (int t = 0; t < 4; ++t)
      *(f32x4*)&T[(t * 16 + li) * 68 + w * 16 + g * 4] = acc[t];
    __syncthreads();
    const int s = otile >> 2;  // 0=q 1=k 2=v
    if (s < 2) {
      unsigned short* dst = s ? khl : qhl;
#pragma unroll
      for (int it = 0; it < 2; ++it) {
        const int n = tid & 63, oct = (tid >> 6) + it * 4;  // 0..7
        short8 h8, l8;
#pragma unroll
        for (int e = 0; e < 8; ++e) {
          unsigned short h, l;
          split_hl(T[n * 68 + oct * 8 + e], h, l);
          h8[e] = (short)h;
          l8[e] = (short)l;
        }
        const int og = otile * 64 + oct * 8;
        const int h = (og >> 5) & 7;
        const int bh = b * 8 + h;
        const int ng = ntile * 64 + n;
        const int dc = oct & 3;  // d-chunk within head
        unsigned short* row = (s ? khl : qhl) + ((size_t)bh * NTOK + ng) * 64;
        *(short8*)&row[(dc ^ (ng & 7)) << 3] = h8;
        *(short8*)&row[((dc + 4) ^ (ng & 7)) << 3] = l8;
      }
      (void)dst;
    } else {
      // v: single bf16, rows = d, cols = j
#pragma unroll
      for (int hh = 0; hh < 2; ++hh) {
        const int d = tid & 31, joct = tid >> 5;  // 0..7
        short8 v8;
#pragma unroll
        for (int e = 0; e < 8; ++e)
          v8[e] = (short)bf16r(T[(joct * 8 + e) * 68 + hh * 32 + d]);
        const int o = otile * 64 + hh * 32 + d;
        const int bh = b * 8 + ((o >> 5) & 7);
        unsigned short* base = vhl + (((size_t)bh * NJT + ntile) * 32 + d) * 64;
        *(short8*)&base[(joct ^ (d & 7)) << 3] = v8;
      }
    }
  }
}

// ---------------------------------------------------------------------------
// MFMA flash attention, 2-phase pipelined staging, deferred-l + defer-max.
// Epilogue writes aoT hi/lo split in proj B-operand layout.
// grid (36, 32), block 256
// ---------------------------------------------------------------------------
__global__ __launch_bounds__(256) void attn_mfma(const unsigned short* __restrict__ qhl,
                                                 const unsigned short* __restrict__ khl,
                                                 const unsigned short* __restrict__ vhl,
                                                 unsigned short* __restrict__ aoT) {
  __shared__ __align__(128) char smem[32768];
  // layout: K dbuf 2x8KB @0 ; V dbuf 2x4KB @16384 ; P 4x2KB @24576
  const int tid = threadIdx.x;
  const int w = tid >> 6, L = tid & 63;
  const int g = L >> 4, li = L & 15, sw = li & 7;
  const int bh = blockIdx.y, ntile = blockIdx.x;
  const int i0 = ntile * 64 + w * 16;

  const size_t qrow = ((size_t)bh * NTOK + i0 + li) * 64;
  const short8 qhi = *(const short8*)&qhl[qrow + ((g ^ sw) << 3)];
  const short8 qlo = *(const short8*)&qhl[qrow + (((g + 4) ^ sw) << 3)];

  f32x4 o0 = {0.f, 0.f, 0.f, 0.f}, o1 = {0.f, 0.f, 0.f, 0.f};
  float m[4], l[4];
#pragma unroll
  for (int r = 0; r < 4; ++r) { m[r] = -INFINITY; l[r] = 0.f; }

  const char* kslab = (const char*)(khl + (size_t)bh * NTOK * 64);
  const char* vslab = (const char*)(vhl + (size_t)bh * NJT * 2048);
  unsigned short* pw = (unsigned short*)(smem + 24576 + w * 2048);

  auto stage = [&](int jt) {
    const int p = jt & 1;
    const char* ks = kslab + (size_t)jt * 8192;
    char* kd = smem + p * 8192;
    glds16(ks + w * 2048 + L * 16, kd + w * 2048);
    glds16(ks + w * 2048 + 1024 + L * 16, kd + w * 2048 + 1024);
    const char* vs = vslab + (size_t)jt * 4096;
    char* vd = smem + 16384 + p * 4096;
    glds16(vs + w * 1024 + L * 16, vd + w * 1024);
  };

  stage(0);
  for (int jt = 0; jt < NJT; ++jt) {
    __syncthreads();  // stage(jt) landed; all waves done with buf jt-1
    if (jt + 1 < NJT) stage(jt + 1);
    const char* Kb = smem + (jt & 1) * 8192;
    const char* Vb = smem + 16384 + (jt & 1) * 4096;

    // ---- QK^T: 4 j-subtiles, 3-way hi/lo split ----
    f32x4 sc[4];
#pragma unroll
    for (int t = 0; t < 4; ++t) {
      const char* kr = Kb + (t * 16 + li) * 128;
      const short8 khi = *(const short8*)(kr + ((g ^ sw) << 4));
      const short8 klo = *(const short8*)(kr + (((g + 4) ^ sw) << 4));
      f32x4 c = {0.f, 0.f, 0.f, 0.f};
      c = __builtin_amdgcn_mfma_f32_16x16x32_bf16(qhi, khi, c, 0, 0, 0);
      c = __builtin_amdgcn_mfma_f32_16x16x32_bf16(qlo, khi, c, 0, 0, 0);
      c = __builtin_amdgcn_mfma_f32_16x16x32_bf16(qhi, klo, c, 0, 0, 0);
      sc[t] = c;
    }

    // ---- online softmax: defer-max + per-lane partial l ----
#pragma unroll
    for (int r = 0; r < 4; ++r) {
      const float lmx = fmaxf(fmaxf(sc[0][r], sc[1][r]), fmaxf(sc[2][r], sc[3][r]));
      if (__any(lmx > m[r] + 8.f)) {
        float mx = lmx;
#pragma unroll
        for (int off = 1; off < 16; off <<= 1) mx = fmaxf(mx, __shfl_xor(mx, off, 64));
        const float nm = fmaxf(m[r], mx);
        const float corr = __expf(m[r] - nm);  // 0 on first tile
        m[r] = nm;
        l[r] *= corr;
        o0[r] *= corr;
        o1[r] *= corr;
      }
      const int il = g * 4 + r;
      float lp = 0.f;
#pragma unroll
      for (int t = 0; t < 4; ++t) {
        const float p = __expf(sc[t][r] - m[r]);
        lp += p;
        pw[il * 64 + (((t * 2 + (li >> 3)) ^ (il & 7)) << 3) + (li & 7)] = bf16r(p);
      }
      l[r] += lp;  // per-lane partial; reduced once at the end
    }

    // ---- PV ----
#pragma unroll
    for (int ksb = 0; ksb < 2; ++ksb) {
      const short8 pa = *(const short8*)((const char*)pw + li * 128 + (((ksb * 4 + g) ^ sw) << 4));
      const short8 vb0 = *(const short8*)(Vb + li * 128 + (((ksb * 4 + g) ^ sw) << 4));
      const short8 vb1 = *(const short8*)(Vb + (16 + li) * 128 + (((ksb * 4 + g) ^ sw) << 4));
      o0 = __builtin_amdgcn_mfma_f32_16x16x32_bf16(pa, vb0, o0, 0, 0, 0);
      o1 = __builtin_amdgcn_mfma_f32_16x16x32_bf16(pa, vb1, o1, 0, 0, 0);
    }
  }

  // final l reduction across the row's 16 lanes
#pragma unroll
  for (int r = 0; r < 4; ++r) {
#pragma unroll
    for (int off = 1; off < 16; off <<= 1) l[r] += __shfl_xor(l[r], off, 64);
  }

  // ---- epilogue: normalize, bounce via LDS, write aoT hi/lo split ----
  __syncthreads();
  float* T = (float*)smem;  // [64 q][36 words]
#pragma unroll
  for (int r = 0; r < 4; ++r) {
    const float inv = 1.f / l[r];
    const int q = w * 16 + g * 4 + r;
    T[q * 36 + li] = o0[r] * inv;
    T[q * 36 + 16 + li] = o1[r] * inv;
  }
  __syncthreads();
  const int q = tid & 63, coct = tid >> 6;  // coct 0..3 (32 c's of this head)
  short8 h8, l8;
#pragma unroll
  for (int e = 0; e < 8; ++e) {
    unsigned short h, lo;
    split_hl(T[q * 36 + coct * 8 + e], h, lo);
    h8[e] = (short)h;
    l8[e] = (short)lo;
  }
  const int h = bh & 7, b = bh >> 3;
  unsigned short* base = aoT + ((size_t)((b * NNT + ntile) * 8 + h)) * 4096 + q * 64;
  *(short8*)&base[(coct ^ (q & 7)) << 3] = h8;
  *(short8*)&base[((coct + 4) ^ (q & 7)) << 3] = l8;
}

// ---------------------------------------------------------------------------
extern "C" void kernel_launch(void* const* d_in, const int* in_sizes, int n_in,
                              void* d_out, int out_size, void* d_ws, size_t ws_size,
                              hipStream_t stream) {
  const float* x      = (const float*)d_in[0];
  const float* w_qkv  = (const float*)d_in[1];
  const float* w_proj = (const float*)d_in[2];
  const float* b_proj = (const float*)d_in[3];
  float* out = (float*)d_out;

  unsigned short* qhl = (unsigned short*)d_ws;              // 32*2304*64
  unsigned short* khl = qhl + (size_t)NBH * NTOK * 64;      // 32*2304*64
  unsigned short* vhl = khl + (size_t)NBH * NTOK * 64;      // 32*36*2048
  unsigned short* xhl = vhl + (size_t)NBH * NJT * 2048;     // 4*36*8*4096 (aliased as aoT)
  unsigned short* whl = xhl + (size_t)BATCH * NNT * 8 * 4096;  // 16*8*4096
  unsigned short* whlp = whl + (size_t)12 * 8 * 4096;
  unsigned short* aoT = xhl;  // alias: xhl dead after gemm_qkv

  prep_w<<<dim3(12, 8), 256, 0, stream>>>(w_qkv, whl, 256, SCALE);
  prep_w<<<dim3(4, 8), 256, 0, stream>>>(w_proj, whlp, 0, 1.f);
  prep_x<<<dim3(NNT, 8, BATCH), 256, 0, stream>>>(x, xhl);

  gemm_mfma<0><<<dim3(NNT, 12, BATCH), 256, 0, stream>>>(whl, xhl, qhl, khl, vhl,
                                                         nullptr, nullptr);

  attn_mfma<<<dim3(NNT, NBH), 256, 0, stream>>>(qhl, khl, vhl, aoT);

  gemm_mfma<1><<<dim3(NNT, 4, BATCH), 256, 0, stream>>>(whlp, aoT, nullptr, nullptr,
                                                        nullptr, out, b_proj);
}